// Round 7
// baseline (196.520 us; speedup 1.0000x reference)
//
#include <hip/hip_runtime.h>
#include <cstdint>

#define T_  2048
#define D_  64
#define BH_ 32
#define W_  256

typedef float f32x4 __attribute__((ext_vector_type(4)));
using bf16x8 = __attribute__((ext_vector_type(8))) short;   // 8 bf16 in 4 VGPRs

__device__ inline unsigned short f2bf(float x) {            // RNE fp32->bf16
  unsigned u = __float_as_uint(x);
  u = (u + 0x7fffu + ((u >> 16) & 1u)) >> 16;
  return (unsigned short)u;
}

// K1: per (bh, 128-row tile): (a) convert pop rows to bf16, (b) sliding-window
// scan -> gene fitness with analytic rowsum normalization folded in -> bf16.
__global__ __launch_bounds__(256) void k1_prep(const float* __restrict__ pop,
                                               unsigned short* __restrict__ pop16,
                                               unsigned short* __restrict__ gfs16) {
  const int unit = blockIdx.x;            // 0..511
  const int i0   = (unit & 15) * 128;
  const int bh   = unit >> 4;
  const int tid  = threadIdx.x;
  const float* Pb = pop + (size_t)bh * T_ * D_;

  // ---- pop -> bf16 (rows i0..i0+127, each row exactly once across grid) ----
  {
    unsigned short* Qb = pop16 + (size_t)bh * T_ * D_;
    for (int e = tid; e < 128 * D_ / 4; e += 256) {
      const int row = e >> 4, d4 = e & 15;
      const f32x4 v = *reinterpret_cast<const f32x4*>(&Pb[(size_t)(i0 + row) * D_ + d4 * 4]);
      uint2 pk;
      pk.x = (unsigned)f2bf(v.x) | ((unsigned)f2bf(v.y) << 16);
      pk.y = (unsigned)f2bf(v.z) | ((unsigned)f2bf(v.w) << 16);
      *reinterpret_cast<uint2*>(&Qb[(size_t)(i0 + row) * D_ + d4 * 4]) = pk;
    }
  }

  // ---- gene fitness rows i0..i0+127 -> gfs16 (rowsum folded, closed form) ----
  const int w = tid >> 6;                 // 4 waves x 32 rows
  const int d = tid & 63;                 // lane == feature dim
  const int ib = i0 + w * 32;
  const float* P = Pb + d;
  unsigned short* G = gfs16 + (size_t)bh * T_ * D_ + d;

  int s0 = ib - (W_ - 1); if (s0 < 0) s0 = 0;
  const int jend = ib + 1;
  float p0=0.f,p1=0.f,p2=0.f,p3=0.f,p4=0.f,p5=0.f,p6=0.f,p7=0.f;
  int j = s0;
  for (; j + 8 <= jend; j += 8) {
    p0 += P[(size_t)(j+0)*D_]; p1 += P[(size_t)(j+1)*D_];
    p2 += P[(size_t)(j+2)*D_]; p3 += P[(size_t)(j+3)*D_];
    p4 += P[(size_t)(j+4)*D_]; p5 += P[(size_t)(j+5)*D_];
    p6 += P[(size_t)(j+6)*D_]; p7 += P[(size_t)(j+7)*D_];
  }
  for (; j < jend; ++j) p0 += P[(size_t)j*D_];
  float isum = ((p0+p1)+(p2+p3)) + ((p4+p5)+(p6+p7));

  for (int r = 0; r < 32; ++r) {
    const int i = ib + r;
    if (r > 0) {
      isum += P[(size_t)i * D_];
      const int jd = i - W_;
      if (jd >= 0) isum -= P[(size_t)jd * D_];
    }
    const float cnt   = (i + 1 < W_) ? (float)(i + 1) : (float)W_;
    const float denom = isum / cnt + 0.5f;
    const float rinv  = 1.0f / denom;
    float s = rinv;
    #pragma unroll
    for (int m = 32; m >= 1; m >>= 1) s += __shfl_xor(s, m);
    float rowsum = cnt * (64.0f / s - 0.5f);
    rowsum = fmaxf(rowsum, 1e-10f);
    G[(size_t)i * D_] = f2bf(rinv / (rowsum * s));
  }
}

// K2: fused band (MFMA, LDS-free) + zero-fill. XCD-safe role interleave:
// within each group of 16 blocks, first 8 are band, next 8 are zero -> every
// XCD (bid%8 round-robin) gets an equal mix. Disjoint write regions.
__global__ __launch_bounds__(256) void k2_band_zero(const unsigned short* __restrict__ pop16,
                                                    const unsigned short* __restrict__ gfs16,
                                                    float* __restrict__ out) {
  const int bid  = blockIdx.x;
  const int unit = (bid >> 4) * 8 + (bid & 7);   // 0..511
  const int i0   = (unit & 15) * 128;
  const int bh   = unit >> 4;
  const int tid  = threadIdx.x;
  float* Ob = out + (size_t)bh * T_ * T_;

  if (bid & 8) {
    // -------- zero-fill role: NT f32x4 streaming of out-of-strip segments ----
    const int w = tid >> 6, lane = tid & 63;
    int L = i0 - 256; if (L < 0) L = 0;
    const int L4  = L >> 2;
    const int R   = i0 + 128;
    const int W4r = (T_ - R) >> 2;
    const f32x4 z4 = {0.f, 0.f, 0.f, 0.f};
    for (int r = w; r < 128; r += 4) {
      float* orow = Ob + (size_t)(i0 + r) * T_;
      f32x4* o4L = reinterpret_cast<f32x4*>(orow);
      for (int c = lane; c < L4; c += 64)
        __builtin_nontemporal_store(z4, &o4L[c]);
      f32x4* o4R = reinterpret_cast<f32x4*>(orow + R);
      for (int c = lane; c < W4r; c += 64)
        __builtin_nontemporal_store(z4, &o4R[c]);
    }
    return;
  }

  // -------- band role: 128x384 strip via mfma_f32_16x16x32_bf16 --------
  // Wave wv owns i-subtiles [ib0, ib0+16) and [ib0+16, ib0+32).
  // Fragment layouts (gfx950): A lane: row=l&15, k=(l>>4)*8+j (8 consec d's ->
  // one 16B load from row-major [row][d]); B lane: col=l&15, k=(l>>4)*8+j
  // (pop^T fragment == row-major pop row l&15); C/D: col=lane&15,
  // row=(lane>>4)*4+reg  [guide-verified m89/m91].
  const int lane = tid & 63, wv = tid >> 6;
  const int l15 = lane & 15, l4 = lane >> 4;
  const unsigned short* Gb = gfs16 + (size_t)bh * T_ * D_;
  const unsigned short* Qb = pop16 + (size_t)bh * T_ * D_;
  const int ib0 = i0 + wv * 32;

  const bf16x8 a00 = *reinterpret_cast<const bf16x8*>(&Gb[(size_t)(ib0      + l15) * D_      + l4 * 8]);
  const bf16x8 a01 = *reinterpret_cast<const bf16x8*>(&Gb[(size_t)(ib0      + l15) * D_ + 32 + l4 * 8]);
  const bf16x8 a10 = *reinterpret_cast<const bf16x8*>(&Gb[(size_t)(ib0 + 16 + l15) * D_      + l4 * 8]);
  const bf16x8 a11 = *reinterpret_cast<const bf16x8*>(&Gb[(size_t)(ib0 + 16 + l15) * D_ + 32 + l4 * 8]);

  for (int jt = 0; jt < 24; ++jt) {
    const int jb = i0 - 256 + jt * 16;
    if (jb < 0) continue;                  // uniform across block
    const bf16x8 b0 = *reinterpret_cast<const bf16x8*>(&Qb[(size_t)(jb + l15) * D_      + l4 * 8]);
    const bf16x8 b1 = *reinterpret_cast<const bf16x8*>(&Qb[(size_t)(jb + l15) * D_ + 32 + l4 * 8]);
    f32x4 c0 = {0.f, 0.f, 0.f, 0.f};
    f32x4 c1 = {0.f, 0.f, 0.f, 0.f};
    c0 = __builtin_amdgcn_mfma_f32_16x16x32_bf16(a00, b0, c0, 0, 0, 0);
    c0 = __builtin_amdgcn_mfma_f32_16x16x32_bf16(a01, b1, c0, 0, 0, 0);
    c1 = __builtin_amdgcn_mfma_f32_16x16x32_bf16(a10, b0, c1, 0, 0, 0);
    c1 = __builtin_amdgcn_mfma_f32_16x16x32_bf16(a11, b1, c1, 0, 0, 0);

    const int jcol = jb + l15;
    #pragma unroll
    for (int r = 0; r < 4; ++r) {
      const int ia = ib0 + l4 * 4 + r;
      const float v0 = ((unsigned)(ia - jcol) < 256u) ? c0[r] : 0.f;
      __builtin_nontemporal_store(v0, &Ob[(size_t)ia * T_ + jcol]);
      const int ibb = ib0 + 16 + l4 * 4 + r;
      const float v1 = ((unsigned)(ibb - jcol) < 256u) ? c1[r] : 0.f;
      __builtin_nontemporal_store(v1, &Ob[(size_t)ibb * T_ + jcol]);
    }
  }
}

extern "C" void kernel_launch(void* const* d_in, const int* in_sizes, int n_in,
                              void* d_out, int out_size, void* d_ws, size_t ws_size,
                              hipStream_t stream) {
  const float* pop = (const float*)d_in[0];
  float* out = (float*)d_out;
  unsigned short* pop16 = (unsigned short*)d_ws;                        // 8.39 MB
  unsigned short* gfs16 = (unsigned short*)((char*)d_ws + (size_t)BH_ * T_ * D_ * 2);

  dim3 blk(256);
  hipLaunchKernelGGL(k1_prep, dim3(16 * BH_), blk, 0, stream, pop, pop16, gfs16);
  hipLaunchKernelGGL(k2_band_zero, dim3(2 * 16 * BH_), blk, 0, stream, pop16, gfs16, out);
}